// Round 6
// baseline (163.933 us; speedup 1.0000x reference)
//
#include <hip/hip_runtime.h>

#define N_ROWS 128
#define IN_DIM 1024
#define OUT_DIM 1024

// out[n,o] = max_k(w[o,k] + x[n,k]) + bias[o]   (tropical matmul)
//
// R6: 16-wave block = w-amortization WITHOUT K-split.
// R5 post-mortem: K-split quadrupled the butterfly (524k shfl), added a
// scratch round-trip + barrier, and its 4-step main loop never amortized
// pipeline fill -> warm kernel ~24us (worse than R3's 13.1).
// This round: block = 1024 threads = 16 waves arranged 4(n) x 4(o), each
// wave = proven R3 shape (2n x 16o, r=4 w-rows/lane, 16-step K loop).
//   Block tile 8n x 64o -> w multiplicity 16 -> w L2 traffic 64 MB
//   (R3: 268 MB @ ~20 TB/s = the measured 13us bottleneck).
//   Grid 16 n x 16 o = 256 blocks = 1 block/CU = 4 waves/SIMD (R3 TLP).
//   Butterfly back to 131k shfl total; single barrier; no scratch.
// Model: LDS 4.3us, VALU 2.8us, VMEM-L2 2.1us -> warm ~5-7us.
// MEASUREMENT: 8 idempotent launches; marginal vs 71.8 single-launch
// anchor gives warm kernel time. Predicted dur_us 100-110.
// XCD: same-bo blocks have idx%8==bo%8 -> same XCD; w/XCD = 512KB (L2).

__global__ __launch_bounds__(1024, 4)
void tropical_linear_kernel(const float* __restrict__ x,
                            const float* __restrict__ w,
                            const float* __restrict__ bias,
                            float* __restrict__ out) {
    __shared__ float4 xs[8 * 256];   // 32 KB: 8 n-rows x 1024 k

    const int tid  = threadIdx.x;
    const int wid  = tid >> 6;       // wave 0..15
    const int lane = tid & 63;
    const int g    = lane & 15;      // k phase 0..15
    const int og   = lane >> 4;      // o group 0..3
    const int wn   = wid >> 2;       // wave n-sub 0..3 (rows 2wn,2wn+1)
    const int wo   = wid & 3;        // wave o-sub 0..3

    const int bn = blockIdx.x >> 4;  // 16 n-blocks
    const int bo = blockIdx.x & 15;  // 16 o-blocks (idx%8==bo%8 -> same XCD)
    const int n0 = bn * 8;
    const int obase = bo * 64 + wo * 16 + og * 4;

    const float4* __restrict__ x4 = (const float4*)x;

    // ---- stage x tile: 2048 float4, 2 per thread, coalesced ----
#pragma unroll
    for (int i = 0; i < 2; ++i) {
        const int idx = tid + i * 1024;
        xs[idx] = x4[(size_t)(n0 + (idx >> 8)) * 256 + (idx & 255)];
    }

    // w row pointers (row stride 4096 B > 13-bit imm, so 4 bases; the
    // 16 k-steps per row fold into imm offsets t*256 B <= 3840).
    const float4* __restrict__ wp0 = (const float4*)w + (size_t)(obase + 0) * 256 + g;
    const float4* __restrict__ wp1 = (const float4*)w + (size_t)(obase + 1) * 256 + g;
    const float4* __restrict__ wp2 = (const float4*)w + (size_t)(obase + 2) * 256 + g;
    const float4* __restrict__ wp3 = (const float4*)w + (size_t)(obase + 3) * 256 + g;

    // w prologue loads (t=0,1) issued before the barrier: independent of LDS
    float4 wA[4], wB[4];
    wA[0] = wp0[0];  wA[1] = wp1[0];  wA[2] = wp2[0];  wA[3] = wp3[0];
    wB[0] = wp0[16]; wB[1] = wp1[16]; wB[2] = wp2[16]; wB[3] = wp3[16];

    float acc[2][4];
#pragma unroll
    for (int j = 0; j < 2; ++j)
#pragma unroll
        for (int r = 0; r < 4; ++r) acc[j][r] = -3.4e38f;

    __syncthreads();

    // this wave's rows: 2wn, 2wn+1; LDS f4 addr = (2wn+j)*256 + t*16 + g
    const float4* __restrict__ xsg = xs + wn * 512 + g;

    float4 xA[2], xB[2];
#pragma unroll
    for (int j = 0; j < 2; ++j) xA[j] = xsg[j * 256];    // t=0

#define TROPIC_STEP(WBUF, XBUF)                                   \
    _Pragma("unroll")                                             \
    for (int j = 0; j < 2; ++j) {                                 \
        const float4 xv = XBUF[j];                                \
        _Pragma("unroll")                                         \
        for (int r = 0; r < 4; ++r) {                             \
            const float s0 = WBUF[r].x + xv.x;                    \
            const float s1 = WBUF[r].y + xv.y;                    \
            const float s2 = WBUF[r].z + xv.z;                    \
            const float s3 = WBUF[r].w + xv.w;                    \
            const float m = fmaxf(fmaxf(s0, s1), s2);             \
            acc[j][r] = fmaxf(fmaxf(m, s3), acc[j][r]);           \
        }                                                         \
    }

    // Steady state: 7 iterations x 2 k-steps; tail handles t=14,15.
#pragma unroll 1
    for (int tt = 0; tt < 7; ++tt) {
        const int t0 = 2 * tt;
        // ---- step t0: consume (wA, xA) ----
#pragma unroll
        for (int j = 0; j < 2; ++j) xB[j] = xsg[j * 256 + (t0 + 1) * 16];
        TROPIC_STEP(wA, xA)
        // reload wA for t0+2 right after last use (2-step lead)
        wA[0] = wp0[(t0 + 2) * 16]; wA[1] = wp1[(t0 + 2) * 16];
        wA[2] = wp2[(t0 + 2) * 16]; wA[3] = wp3[(t0 + 2) * 16];
        // ---- step t1: consume (wB, xB) ----
#pragma unroll
        for (int j = 0; j < 2; ++j) xA[j] = xsg[j * 256 + (t0 + 2) * 16];
        TROPIC_STEP(wB, xB)
        wB[0] = wp0[(t0 + 3) * 16]; wB[1] = wp1[(t0 + 3) * 16];
        wB[2] = wp2[(t0 + 3) * 16]; wB[3] = wp3[(t0 + 3) * 16];
    }
    // ---- tail: t=14 (wA,xA), t=15 (wB,xB) ----
#pragma unroll
    for (int j = 0; j < 2; ++j) xB[j] = xsg[j * 256 + 15 * 16];
    TROPIC_STEP(wA, xA)
    TROPIC_STEP(wB, xB)

#undef TROPIC_STEP

    // ---- reduce across the 16 k-phases (lane bits 0..3) ----
#pragma unroll
    for (int j = 0; j < 2; ++j) {
#pragma unroll
        for (int r = 0; r < 4; ++r) {
            float v = acc[j][r];
            v = fmaxf(v, __shfl_xor(v, 1, 64));
            v = fmaxf(v, __shfl_xor(v, 2, 64));
            v = fmaxf(v, __shfl_xor(v, 4, 64));
            v = fmaxf(v, __shfl_xor(v, 8, 64));
            acc[j][r] = v;
        }
    }

    // After the butterfly all 16 g-lanes in an og group hold identical
    // acc; lanes g<4 each store one float2: j = g&1, col pair pr = g>>1.
    if (g < 4) {
        const int jj = g & 1;        // n-row within wave pair
        const int pr = g >> 1;       // which float2 column pair
        float2 res = make_float2(0.f, 0.f);
#pragma unroll
        for (int j = 0; j < 2; ++j) {
            if (jj == j) {           // static indices only
                res.x = pr ? acc[j][2] : acc[j][0];
                res.y = pr ? acc[j][3] : acc[j][1];
            }
        }
        const int oc = obase + pr * 2;
        const float2 bv = *(const float2*)&bias[oc];
        res.x += bv.x;
        res.y += bv.y;
        *(float2*)&out[(size_t)(n0 + wn * 2 + jj) * OUT_DIM + oc] = res;
    }
}

extern "C" void kernel_launch(void* const* d_in, const int* in_sizes, int n_in,
                              void* d_out, int out_size, void* d_ws, size_t ws_size,
                              hipStream_t stream) {
    const float* x    = (const float*)d_in[0];   // [128,1024]
    const float* w    = (const float*)d_in[1];   // [1024,1024]
    const float* bias = (const float*)d_in[2];   // [1024]
    float* out = (float*)d_out;                  // [128,1024]

    dim3 grid(256);
    dim3 block(1024);
    // 8 idempotent launches: marginal cost per launch = warm kernel time.
    // (Measurement instrument — will revert to single launch once the
    // structure question is settled. See R6 header comment.)
    for (int rep = 0; rep < 8; ++rep) {
        hipLaunchKernelGGL(tropical_linear_kernel, grid, block, 0, stream,
                           x, w, bias, out);
    }
}